// Round 2
// baseline (27728.857 us; speedup 1.0000x reference)
//
#include <hip/hip_runtime.h>
#include <math.h>

typedef _Float16 f16;
typedef f16 f16x4 __attribute__((ext_vector_type(4)));
typedef f16 f16x8 __attribute__((ext_vector_type(8)));
typedef float f32x4 __attribute__((ext_vector_type(4)));

#define NB 128      // batch
#define TT 256      // time steps
#define DD 1024     // input dim
#define HH 1024     // hidden dim
#define PP 196      // spatial positions
#define K3 3072     // folded K = D + H + H
#define FOURH 4096
#define NBLK 256
#define NTHR 512

// ---------------- P1: h0 = c0 = mean_p A[n][h][:]  ----------------
__global__ void k_h0(const float* __restrict__ A, float* __restrict__ c_state,
                     f16* __restrict__ act_h0) {
  int idx = blockIdx.x * 256 + threadIdx.x;            // (n*1024 + h)
  const float4* ap = (const float4*)(A + (size_t)idx * PP);
  float s = 0.f;
#pragma unroll
  for (int i = 0; i < PP / 4; ++i) { float4 v = ap[i]; s += v.x + v.y + v.z + v.w; }
  float m = s * (1.0f / PP);
  c_state[idx] = m;
  act_h0[idx] = (f16)m;
}

// ---------------- P2: A[n][h][p] fp32 -> A2[n][p][h] fp16 ----------------
__global__ void k_At(const float* __restrict__ A, f16* __restrict__ A2) {
  __shared__ float tile[32][33];
  int p0 = blockIdx.x * 32, h0 = blockIdx.y * 32, n = blockIdx.z;
  for (int i = threadIdx.x; i < 1024; i += 256) {
    int r = i >> 5, c = i & 31;
    int p = p0 + c;
    float v = 0.f;
    if (p < PP) v = A[((size_t)n * HH + h0 + r) * PP + p];
    tile[r][c] = v;
  }
  __syncthreads();
  for (int i = threadIdx.x; i < 1024; i += 256) {
    int r = i >> 5, c = i & 31;
    int p = p0 + r;
    if (p < PP) A2[((size_t)n * PP + p) * HH + h0 + c] = (f16)tile[c][r];
  }
}

// ------ P3: Wt[j][k] fp16, col-major weights, k = [Wx;Wh;Wattn] ----------
__global__ void k_Wt(const float* __restrict__ Wx, const float* __restrict__ Wh,
                     const float* __restrict__ Wa, f16* __restrict__ Wt) {
  __shared__ float tile[32][33];
  int k0 = blockIdx.x * 32, j0 = blockIdx.y * 32;
  const float* src; int kb;
  if (k0 < 1024)      { src = Wx; kb = k0; }
  else if (k0 < 2048) { src = Wh; kb = k0 - 1024; }
  else                { src = Wa; kb = k0 - 2048; }
  for (int i = threadIdx.x; i < 1024; i += 256) {
    int r = i >> 5, c = i & 31;
    tile[r][c] = src[(size_t)(kb + r) * FOURH + j0 + c];
  }
  __syncthreads();
  for (int i = threadIdx.x; i < 1024; i += 256) {
    int r = i >> 5, c = i & 31;
    Wt[(size_t)(j0 + r) * K3 + k0 + c] = (f16)tile[c][r];
  }
}

// ---------------- P4: x fp32 -> fp16 ----------------
__global__ void k_xcvt(const float* __restrict__ x, f16* __restrict__ xh) {
  size_t i = (size_t)blockIdx.x * 256 + threadIdx.x;
  float4 v = ((const float4*)x)[i];
  f16x4 o; o[0] = (f16)v.x; o[1] = (f16)v.y; o[2] = (f16)v.z; o[3] = (f16)v.w;
  *(f16x4*)(xh + i * 4) = o;
}

// ---------------- hierarchical grid barrier (cooperative launch) -------------
// bar[0..255]: 16 leaf counters at bar[i*16]; bar[256]: root; bar[272]: gen.
// Monotonic counters (no reset races); memset once per kernel_launch call.
__device__ __forceinline__ void grid_barrier(unsigned* bar) {
  __syncthreads();
  if (threadIdx.x == 0) {
    __threadfence();                                    // release my block's writes
    unsigned* leaf = bar + (blockIdx.x & 15) * 16;
    unsigned* root = bar + 256;
    unsigned* gen  = bar + 272;
    unsigned g = __hip_atomic_load(gen, __ATOMIC_RELAXED, __HIP_MEMORY_SCOPE_AGENT);
    unsigned lv = __hip_atomic_fetch_add(leaf, 1u, __ATOMIC_ACQ_REL, __HIP_MEMORY_SCOPE_AGENT);
    if ((lv & 15u) == 15u) {                            // last of this leaf's cohort
      unsigned rv = __hip_atomic_fetch_add(root, 1u, __ATOMIC_ACQ_REL, __HIP_MEMORY_SCOPE_AGENT);
      if ((rv & 15u) == 15u)
        __hip_atomic_fetch_add(gen, 1u, __ATOMIC_RELEASE, __HIP_MEMORY_SCOPE_AGENT);
    }
    while (__hip_atomic_load(gen, __ATOMIC_RELAXED, __HIP_MEMORY_SCOPE_AGENT) == g)
      __builtin_amdgcn_s_sleep(2);
    __threadfence();                                    // acquire others' writes
  }
  __syncthreads();
}

// ---------------- persistent per-step kernel (cooperative) ----------------
// 256 blocks x 512 threads. Per step: S (scores) | A (softmax+attn) | G (gemm+LSTM).
// c-state lives in a register per thread for all 256 steps.
__global__ __launch_bounds__(NTHR, 2) void k_steps(
    const f16* __restrict__ xh, const f16* __restrict__ A2,
    const f16* __restrict__ Wt, const float* __restrict__ bias,
    const float* __restrict__ c0,
    f16* __restrict__ acth0, f16* __restrict__ acth1,
    f16* __restrict__ attnb, float* __restrict__ scores,
    float* __restrict__ out, unsigned* __restrict__ bar) {
  __shared__ float lds[8 * 512 + 256];   // A: red[4096]+wexp[200]+srinv | G: slab[128*17]
  float* red   = lds;
  float* wexp  = lds + 4096;
  float* srinv = lds + 4096 + 200;
  float* slab  = lds;

  int tid = threadIdx.x;
  int lane = tid & 63, wid = tid >> 6;
  int l15 = lane & 15, quad = lane >> 4;
  int bx = blockIdx.x;

  // G geometry: block covers all 128 rows x 16 cols (4 h's x 4 gates)
  int hs4 = bx * 4;
  int gn = tid >> 2, gh = tid & 3;                 // epilogue cell (n, h-local)
  float creg = c0[gn * HH + hs4 + gh];             // c-state in register
  int mhalf = wid & 1, kq = wid >> 1;              // wave: 64 rows, K/4 slice
  int rowbase = mhalf * 64 + l15;
  int jcol = (l15 >> 2) * 1024 + hs4 + (l15 & 3);  // gate*1024 + hs4 + hh
  const f16* Wp = Wt + (size_t)jcol * K3 + quad * 8;

  // S/A geometry
  int n_sa = bx >> 1;
  int half = bx & 1;

  for (int t = 0; t < TT; ++t) {
    const f16* hcur = (t & 1) ? acth1 : acth0;
    f16* hnxt = (t & 1) ? acth0 : acth1;

    // ================= phase S: scores[n][p] = h . A2[n][p][:] / 32 ==========
    {
      const f16x8* hp = (const f16x8*)(hcur + (size_t)n_sa * HH + lane * 16);
      f16x8 hv0 = hp[0], hv1 = hp[1];
      float hf[16];
#pragma unroll
      for (int e = 0; e < 8; ++e) { hf[e] = (float)hv0[e]; hf[8 + e] = (float)hv1[e]; }
      const f16* An = A2 + (size_t)n_sa * PP * HH;
      int pend = half * 98 + 98;
      for (int p = half * 98 + wid; p < pend; p += 8) {
        const f16x8* apv = (const f16x8*)(An + (size_t)p * HH + lane * 16);
        f16x8 a0 = apv[0], a1 = apv[1];
        float acc = 0.f;
#pragma unroll
        for (int e = 0; e < 8; ++e)
          acc += hf[e] * (float)a0[e] + hf[8 + e] * (float)a1[e];
#pragma unroll
        for (int off = 32; off > 0; off >>= 1) acc += __shfl_xor(acc, off, 64);
        if (lane == 0) scores[n_sa * PP + p] = acc * 0.03125f;
      }
    }
    grid_barrier(bar);

    // ================= phase A: softmax + attn[n][h-half] ====================
    {
      if (wid == 0) {        // wave 0 computes softmax table into LDS
        const float* sp = scores + n_sa * PP;
        float s0 = sp[lane], s1 = sp[64 + lane], s2 = sp[128 + lane];
        float s3 = (lane < 4) ? sp[192 + lane] : -1e30f;
        float mx = fmaxf(fmaxf(s0, s1), fmaxf(s2, s3));
#pragma unroll
        for (int off = 32; off > 0; off >>= 1) mx = fmaxf(mx, __shfl_xor(mx, off, 64));
        float e0 = __expf(s0 - mx), e1 = __expf(s1 - mx), e2 = __expf(s2 - mx);
        float e3 = (lane < 4) ? __expf(s3 - mx) : 0.f;
        float ssum = e0 + e1 + e2 + e3;
#pragma unroll
        for (int off = 32; off > 0; off >>= 1) ssum += __shfl_xor(ssum, off, 64);
        wexp[lane] = e0; wexp[64 + lane] = e1; wexp[128 + lane] = e2;
        if (lane < 4) wexp[192 + lane] = e3;
        if (lane == 0) *srinv = 1.f / ssum;
      }
      __syncthreads();
      const f16* Abase = A2 + (size_t)n_sa * PP * HH + half * 512 + lane * 8;
      float acc[8];
#pragma unroll
      for (int e = 0; e < 8; ++e) acc[e] = 0.f;
      for (int p = wid; p < PP; p += 8) {
        f16x8 v = *(const f16x8*)(Abase + (size_t)p * HH);
        float w = wexp[p];
#pragma unroll
        for (int e = 0; e < 8; ++e) acc[e] += w * (float)v[e];
      }
#pragma unroll
      for (int e = 0; e < 8; ++e) red[wid * 512 + lane * 8 + e] = acc[e];
      __syncthreads();
      float s = 0.f;
#pragma unroll
      for (int w = 0; w < 8; ++w) s += red[w * 512 + tid];
      attnb[(size_t)n_sa * HH + half * 512 + tid] = (f16)(s * (*srinv));
    }
    grid_barrier(bar);

    // ================= phase G: a = [x|h|attn]@Wt^T + b; gates; c,h ==========
    {
      f32x4 acc[4];
#pragma unroll
      for (int i = 0; i < 4; ++i)
#pragma unroll
        for (int e = 0; e < 4; ++e) acc[i][e] = 0.f;

      auto seg = [&](const f16* base, size_t rstride, int kgbase, int nks) {
#pragma unroll 4
        for (int ks = 0; ks < nks; ++ks) {
          const f16* ap = base + ks * 32 + quad * 8;
          f16x8 b = *(const f16x8*)(Wp + kgbase + ks * 32);
          f16x8 a0 = *(const f16x8*)(ap + (size_t)(rowbase)      * rstride);
          f16x8 a1 = *(const f16x8*)(ap + (size_t)(rowbase + 16) * rstride);
          f16x8 a2 = *(const f16x8*)(ap + (size_t)(rowbase + 32) * rstride);
          f16x8 a3 = *(const f16x8*)(ap + (size_t)(rowbase + 48) * rstride);
          acc[0] = __builtin_amdgcn_mfma_f32_16x16x32_f16(a0, b, acc[0], 0, 0, 0);
          acc[1] = __builtin_amdgcn_mfma_f32_16x16x32_f16(a1, b, acc[1], 0, 0, 0);
          acc[2] = __builtin_amdgcn_mfma_f32_16x16x32_f16(a2, b, acc[2], 0, 0, 0);
          acc[3] = __builtin_amdgcn_mfma_f32_16x16x32_f16(a3, b, acc[3], 0, 0, 0);
        }
      };
      const f16* xrow = xh + (size_t)t * DD;
      if (kq == 0) {
        seg(xrow, (size_t)TT * DD, 0, 24);
      } else if (kq == 1) {
        seg(xrow + 768, (size_t)TT * DD, 768, 8);
        seg(hcur, HH, 1024, 16);
      } else if (kq == 2) {
        seg(hcur + 512, HH, 1536, 16);
        seg(attnb, HH, 2048, 8);
      } else {
        seg(attnb + 256, HH, 2304, 24);
      }

      if (kq == 0) {
#pragma unroll
        for (int mt = 0; mt < 4; ++mt)
#pragma unroll
          for (int jr = 0; jr < 4; ++jr)
            slab[(mhalf * 64 + mt * 16 + quad * 4 + jr) * 17 + l15] = acc[mt][jr];
      }
      __syncthreads();
      if (kq != 0) {
#pragma unroll
        for (int mt = 0; mt < 4; ++mt)
#pragma unroll
          for (int jr = 0; jr < 4; ++jr)
            atomicAdd(&slab[(mhalf * 64 + mt * 16 + quad * 4 + jr) * 17 + l15],
                      acc[mt][jr]);
      }
      __syncthreads();

      {
        float ai = slab[gn * 17 + gh]      + bias[hs4 + gh];
        float af = slab[gn * 17 + 4 + gh]  + bias[1024 + hs4 + gh];
        float ao = slab[gn * 17 + 8 + gh]  + bias[2048 + hs4 + gh];
        float ag = slab[gn * 17 + 12 + gh] + bias[3072 + hs4 + gh];
        float ig = 1.f / (1.f + __expf(-ai));
        float fg = 1.f / (1.f + __expf(-af));
        float og = 1.f / (1.f + __expf(-ao));
        float gg = tanhf(ag);
        creg = fg * creg + ig * gg;
        float hn = og * tanhf(creg);
        out[((size_t)gn * TT + t) * HH + hs4 + gh] = hn;
        hnxt[gn * HH + hs4 + gh] = (f16)hn;
      }
    }
    grid_barrier(bar);
  }
}

extern "C" void kernel_launch(void* const* d_in, const int* in_sizes, int n_in,
                              void* d_out, int out_size, void* d_ws, size_t ws_size,
                              hipStream_t stream) {
  const float* x  = (const float*)d_in[0];
  const float* A  = (const float*)d_in[1];
  const float* Wx = (const float*)d_in[2];
  const float* Wh = (const float*)d_in[3];
  const float* Wa = (const float*)d_in[4];
  const float* b  = (const float*)d_in[5];
  float* out = (float*)d_out;

  char* ws = (char*)d_ws;
  f16* A2 = (f16*)ws;          ws += (size_t)NB * PP * HH * 2;
  f16* Wt = (f16*)ws;          ws += (size_t)FOURH * K3 * 2;
  f16* xh = (f16*)ws;          ws += (size_t)NB * TT * DD * 2;
  f16* acth0 = (f16*)ws;       ws += (size_t)NB * HH * 2;
  f16* acth1 = (f16*)ws;       ws += (size_t)NB * HH * 2;
  f16* attnb = (f16*)ws;       ws += (size_t)NB * HH * 2;
  float* c0 = (float*)ws;      ws += (size_t)NB * HH * 4;
  float* scores = (float*)ws;  ws += (size_t)NB * PP * 4;
  unsigned* bar = (unsigned*)ws; ws += 4096;

  hipMemsetAsync(bar, 0, 4096, stream);
  k_h0<<<512, 256, 0, stream>>>(A, c0, acth0);
  k_At<<<dim3(7, 32, NB), 256, 0, stream>>>(A, A2);
  k_Wt<<<dim3(96, 128), 256, 0, stream>>>(Wx, Wh, Wa, Wt);
  k_xcvt<<<32768, 256, 0, stream>>>(x, xh);

  void* args[] = { (void*)&xh, (void*)&A2, (void*)&Wt, (void*)&b, (void*)&c0,
                   (void*)&acth0, (void*)&acth1, (void*)&attnb, (void*)&scores,
                   (void*)&out, (void*)&bar };
  hipLaunchCooperativeKernel((const void*)k_steps, dim3(NBLK), dim3(NTHR),
                             args, 0, stream);
}

// Round 3
// 24268.835 us; speedup vs baseline: 1.1426x; 1.1426x over previous
//
#include <hip/hip_runtime.h>
#include <math.h>

typedef _Float16 f16;
typedef f16 f16x2 __attribute__((ext_vector_type(2)));
typedef f16 f16x4 __attribute__((ext_vector_type(4)));
typedef f16 f16x8 __attribute__((ext_vector_type(8)));
typedef float f32x4 __attribute__((ext_vector_type(4)));

#define NB 128      // batch
#define TT 256      // time steps
#define DD 1024     // input dim
#define HH 1024     // hidden dim
#define PP 196      // spatial positions
#define K3 3072     // folded K = D + H + H
#define FOURH 4096
#define NBLK 256
#define NTHR 512
#define WROW 3080   // padded LDS row stride (f16) for Wt slab
// dynamic LDS: wslab 16*3080*2 B + uni 9216 f32
#define LDS_BYTES (16 * WROW * 2 + 9216 * 4)

// ---------------- P1: h0 = c0 = mean_p A[n][h][:]  ----------------
__global__ void k_h0(const float* __restrict__ A, float* __restrict__ c0,
                     f16* __restrict__ act_h0) {
  int idx = blockIdx.x * 256 + threadIdx.x;            // (n*1024 + h)
  const float4* ap = (const float4*)(A + (size_t)idx * PP);
  float s = 0.f;
#pragma unroll
  for (int i = 0; i < PP / 4; ++i) { float4 v = ap[i]; s += v.x + v.y + v.z + v.w; }
  float m = s * (1.0f / PP);
  c0[idx] = m;
  act_h0[idx] = (f16)m;
}

// ---------------- P2: A[n][h][p] fp32 -> A2[n][p][h] fp16 ----------------
__global__ void k_At(const float* __restrict__ A, f16* __restrict__ A2) {
  __shared__ float tile[32][33];
  int p0 = blockIdx.x * 32, h0 = blockIdx.y * 32, n = blockIdx.z;
  for (int i = threadIdx.x; i < 1024; i += 256) {
    int r = i >> 5, c = i & 31;
    int p = p0 + c;
    float v = 0.f;
    if (p < PP) v = A[((size_t)n * HH + h0 + r) * PP + p];
    tile[r][c] = v;
  }
  __syncthreads();
  for (int i = threadIdx.x; i < 1024; i += 256) {
    int r = i >> 5, c = i & 31;
    int p = p0 + r;
    if (p < PP) A2[((size_t)n * PP + p) * HH + h0 + c] = (f16)tile[c][r];
  }
}

// ------ P3: Wt[j][k] fp16, col-major weights, k = [Wx;Wh;Wattn] ----------
__global__ void k_Wt(const float* __restrict__ Wx, const float* __restrict__ Wh,
                     const float* __restrict__ Wa, f16* __restrict__ Wt) {
  __shared__ float tile[32][33];
  int k0 = blockIdx.x * 32, j0 = blockIdx.y * 32;
  const float* src; int kb;
  if (k0 < 1024)      { src = Wx; kb = k0; }
  else if (k0 < 2048) { src = Wh; kb = k0 - 1024; }
  else                { src = Wa; kb = k0 - 2048; }
  for (int i = threadIdx.x; i < 1024; i += 256) {
    int r = i >> 5, c = i & 31;
    tile[r][c] = src[(size_t)(kb + r) * FOURH + j0 + c];
  }
  __syncthreads();
  for (int i = threadIdx.x; i < 1024; i += 256) {
    int r = i >> 5, c = i & 31;
    Wt[(size_t)(j0 + r) * K3 + k0 + c] = (f16)tile[c][r];
  }
}

// ---------------- P4: x fp32 -> fp16 ----------------
__global__ void k_xcvt(const float* __restrict__ x, f16* __restrict__ xh) {
  size_t i = (size_t)blockIdx.x * 256 + threadIdx.x;
  float4 v = ((const float4*)x)[i];
  f16x4 o; o[0] = (f16)v.x; o[1] = (f16)v.y; o[2] = (f16)v.z; o[3] = (f16)v.w;
  *(f16x4*)(xh + i * 4) = o;
}

// ---------------- hierarchical grid barrier (cooperative launch) -------------
__device__ __forceinline__ void grid_barrier(unsigned* bar) {
  __syncthreads();
  if (threadIdx.x == 0) {
    __threadfence();
    unsigned* leaf = bar + (blockIdx.x & 15) * 16;
    unsigned* root = bar + 256;
    unsigned* gen  = bar + 272;
    unsigned g = __hip_atomic_load(gen, __ATOMIC_RELAXED, __HIP_MEMORY_SCOPE_AGENT);
    unsigned lv = __hip_atomic_fetch_add(leaf, 1u, __ATOMIC_ACQ_REL, __HIP_MEMORY_SCOPE_AGENT);
    if ((lv & 15u) == 15u) {
      unsigned rv = __hip_atomic_fetch_add(root, 1u, __ATOMIC_ACQ_REL, __HIP_MEMORY_SCOPE_AGENT);
      if ((rv & 15u) == 15u)
        __hip_atomic_fetch_add(gen, 1u, __ATOMIC_RELEASE, __HIP_MEMORY_SCOPE_AGENT);
    }
    while (__hip_atomic_load(gen, __ATOMIC_RELAXED, __HIP_MEMORY_SCOPE_AGENT) == g)
      __builtin_amdgcn_s_sleep(2);
    __threadfence();
  }
  __syncthreads();
}

// ---------------- persistent per-step kernel (cooperative) ----------------
// 256 blocks x 512 threads, 1 block/CU.
// Block b: S/A role (n = b>>1, h-half = b&1) with A2 slice IN REGISTERS
//          (196 p x 512 h = 104 VGPR/thread, resident all 256 steps);
//          G role: 16 output cols (4 h x 4 gates), Wt slice IN LDS (98.5 KB).
__global__ __launch_bounds__(NTHR, 2) void k_steps(
    const f16* __restrict__ xh, const f16* __restrict__ A2,
    const f16* __restrict__ Wtg, const float* __restrict__ bias,
    const float* __restrict__ c0,
    f16* __restrict__ acth0, f16* __restrict__ acth1,
    f16* __restrict__ attnb, float* __restrict__ spart,
    float* __restrict__ out, unsigned* __restrict__ bar) {
  extern __shared__ char smem[];
  f16* wslab = (f16*)smem;                         // [16][WROW]
  float* uni   = (float*)(smem + 16 * WROW * 2);   // 9216 floats
  float* sc    = uni;                              // [208] scores partial (own)
  float* wexp  = uni + 208;                        // [208] softmax weights (pad 0)
  float* srinv = uni + 416;
  float* red   = uni + 512;                        // [16][32][17] attn partials
  float* slabq = uni;                              // G: [4][128][18]

  int tid = threadIdx.x;
  int lane = tid & 63, wid = tid >> 6;
  int bx = blockIdx.x;

  // ---- S/A geometry ----
  int n = bx >> 1, hhalf = bx & 1;
  int hsub = lane & 31;                    // 32 chunks of 16 h
  int pg = wid * 2 + (lane >> 5);          // 16 p-groups

  // ---- A2 slice into registers (resident forever) ----
  f16x8 areg0[13], areg1[13];
  {
    const f16* Ab = A2 + ((size_t)n * PP) * HH + hhalf * 512 + hsub * 16;
#pragma unroll
    for (int i = 0; i < 13; ++i) {
      int p = pg + 16 * i; if (p >= PP) p = pg;   // dup-load, masked at use
      areg0[i] = *(const f16x8*)(Ab + (size_t)p * HH);
      areg1[i] = *(const f16x8*)(Ab + (size_t)p * HH + 8);
    }
  }

  // ---- Wt slice into LDS (resident forever) ----
#pragma unroll 1
  for (int c = 0; c < 16; ++c) {
    if (tid < 384) {
      int j = (c >> 2) * 1024 + bx * 4 + (c & 3);
      f16x8 v = *(const f16x8*)(Wtg + (size_t)j * K3 + tid * 8);
      *(f16x8*)(wslab + c * WROW + tid * 8) = v;
    }
  }

  // ---- G geometry ----
  int l15 = lane & 15, quad = lane >> 4;
  int mhalf = wid & 1, kq = wid >> 1;
  int rowbase = mhalf * 64 + l15;
  const f16* wlp = wslab + l15 * WROW + quad * 8;
  int gn = tid >> 2, gh = tid & 3;
  int hs4 = bx * 4;
  float creg = c0[gn * HH + hs4 + gh];
  float b_i = bias[hs4 + gh], b_f = bias[1024 + hs4 + gh];
  float b_o = bias[2048 + hs4 + gh], b_g = bias[3072 + hs4 + gh];

  for (int t = 0; t < TT; ++t) {
    const f16* hcur = (t & 1) ? acth1 : acth0;
    f16* hnxt = (t & 1) ? acth0 : acth1;

    // ============ phase S: partial scores over this block's 512 h ============
    {
      const f16x8* hp = (const f16x8*)(hcur + (size_t)n * HH + hhalf * 512 + hsub * 16);
      f16x8 hv0 = hp[0], hv1 = hp[1];
      float hf[16];
#pragma unroll
      for (int e = 0; e < 8; ++e) { hf[e] = (float)hv0[e]; hf[8 + e] = (float)hv1[e]; }
#pragma unroll
      for (int i = 0; i < 13; ++i) {
        float s = 0.f;
#pragma unroll
        for (int e = 0; e < 8; ++e)
          s += hf[e] * (float)areg0[i][e] + hf[8 + e] * (float)areg1[i][e];
        s += __shfl_xor(s, 1, 64);
        s += __shfl_xor(s, 2, 64);
        s += __shfl_xor(s, 4, 64);
        s += __shfl_xor(s, 8, 64);
        s += __shfl_xor(s, 16, 64);
        int p = pg + 16 * i;
        if (hsub == 0 && p < PP) {
          sc[p] = s;
          spart[bx * 256 + p] = s;     // publish partial for partner block
        }
      }
    }
    grid_barrier(bar);

    // ============ phase A: softmax (combine partner) + attn from regs ========
    {
      if (wid == 0) {
        const float* pp = spart + (bx ^ 1) * 256;
        float s0 = (sc[lane]       + pp[lane])       * 0.03125f;
        float s1 = (sc[64 + lane]  + pp[64 + lane])  * 0.03125f;
        float s2 = (sc[128 + lane] + pp[128 + lane]) * 0.03125f;
        float s3 = (lane < 4) ? (sc[192 + lane] + pp[192 + lane]) * 0.03125f : -1e30f;
        float mx = fmaxf(fmaxf(s0, s1), fmaxf(s2, s3));
#pragma unroll
        for (int off = 32; off > 0; off >>= 1) mx = fmaxf(mx, __shfl_xor(mx, off, 64));
        float e0 = __expf(s0 - mx), e1 = __expf(s1 - mx), e2 = __expf(s2 - mx);
        float e3 = (lane < 4) ? __expf(s3 - mx) : 0.f;
        float ssum = e0 + e1 + e2 + e3;
#pragma unroll
        for (int off = 32; off > 0; off >>= 1) ssum += __shfl_xor(ssum, off, 64);
        wexp[lane] = e0; wexp[64 + lane] = e1; wexp[128 + lane] = e2;
        if (lane < 4)  wexp[192 + lane] = e3;
        if (lane < 12) wexp[196 + lane] = 0.f;   // pad so p>=196 contributes 0
        if (lane == 0) *srinv = 1.f / ssum;
      }
      __syncthreads();
      float acc[16];
#pragma unroll
      for (int e = 0; e < 16; ++e) acc[e] = 0.f;
#pragma unroll
      for (int i = 0; i < 13; ++i) {
        float wgt = wexp[pg + 16 * i];
#pragma unroll
        for (int e = 0; e < 8; ++e) {
          acc[e]     += wgt * (float)areg0[i][e];
          acc[8 + e] += wgt * (float)areg1[i][e];
        }
      }
#pragma unroll
      for (int e = 0; e < 16; ++e) red[pg * 544 + hsub * 17 + e] = acc[e];
      __syncthreads();
      float s = 0.f;
      int ra = (tid >> 4) * 17 + (tid & 15);
#pragma unroll
      for (int g = 0; g < 16; ++g) s += red[g * 544 + ra];
      attnb[(size_t)n * HH + hhalf * 512 + tid] = (f16)(s * (*srinv));
    }
    grid_barrier(bar);

    // ============ phase G: gates GEMM (Wt from LDS) + LSTM update ============
    {
      f32x4 acc4[4];
#pragma unroll
      for (int i = 0; i < 4; ++i)
#pragma unroll
        for (int e = 0; e < 4; ++e) acc4[i][e] = 0.f;

      auto seg = [&](const f16* base, size_t rstride, int kgbase, int nks) {
#pragma unroll 4
        for (int ks = 0; ks < nks; ++ks) {
          const f16* ap = base + ks * 32 + quad * 8;
          f16x8 b = *(const f16x8*)(wlp + kgbase + ks * 32);
          f16x8 a0 = *(const f16x8*)(ap + (size_t)(rowbase)      * rstride);
          f16x8 a1 = *(const f16x8*)(ap + (size_t)(rowbase + 16) * rstride);
          f16x8 a2 = *(const f16x8*)(ap + (size_t)(rowbase + 32) * rstride);
          f16x8 a3 = *(const f16x8*)(ap + (size_t)(rowbase + 48) * rstride);
          acc4[0] = __builtin_amdgcn_mfma_f32_16x16x32_f16(a0, b, acc4[0], 0, 0, 0);
          acc4[1] = __builtin_amdgcn_mfma_f32_16x16x32_f16(a1, b, acc4[1], 0, 0, 0);
          acc4[2] = __builtin_amdgcn_mfma_f32_16x16x32_f16(a2, b, acc4[2], 0, 0, 0);
          acc4[3] = __builtin_amdgcn_mfma_f32_16x16x32_f16(a3, b, acc4[3], 0, 0, 0);
        }
      };
      const f16* xrow = xh + (size_t)t * DD;
      if (kq == 0) {
        seg(xrow, (size_t)TT * DD, 0, 24);
      } else if (kq == 1) {
        seg(xrow + 768, (size_t)TT * DD, 768, 8);
        seg(hcur, HH, 1024, 16);
      } else if (kq == 2) {
        seg(hcur + 512, HH, 1536, 16);
        seg(attnb, HH, 2048, 8);
      } else {
        seg(attnb + 256, HH, 2304, 24);
      }

#pragma unroll
      for (int mt = 0; mt < 4; ++mt)
#pragma unroll
        for (int jr = 0; jr < 4; ++jr)
          slabq[kq * 2304 + (mhalf * 64 + mt * 16 + quad * 4 + jr) * 18 + l15] =
              acc4[mt][jr];
      __syncthreads();

      {
        float ai = b_i, af = b_f, ao = b_o, ag = b_g;
#pragma unroll
        for (int q = 0; q < 4; ++q) {
          const float* sl = slabq + q * 2304 + gn * 18;
          ai += sl[gh]; af += sl[4 + gh]; ao += sl[8 + gh]; ag += sl[12 + gh];
        }
        float ig = 1.f / (1.f + __expf(-ai));
        float fg = 1.f / (1.f + __expf(-af));
        float og = 1.f / (1.f + __expf(-ao));
        float gg = tanhf(ag);
        creg = fg * creg + ig * gg;
        float hn = og * tanhf(creg);
        out[((size_t)gn * TT + t) * HH + hs4 + gh] = hn;
        hnxt[gn * HH + hs4 + gh] = (f16)hn;
      }
    }
    grid_barrier(bar);
  }
}

extern "C" void kernel_launch(void* const* d_in, const int* in_sizes, int n_in,
                              void* d_out, int out_size, void* d_ws, size_t ws_size,
                              hipStream_t stream) {
  const float* x  = (const float*)d_in[0];
  const float* A  = (const float*)d_in[1];
  const float* Wx = (const float*)d_in[2];
  const float* Wh = (const float*)d_in[3];
  const float* Wa = (const float*)d_in[4];
  const float* b  = (const float*)d_in[5];
  float* out = (float*)d_out;

  char* ws = (char*)d_ws;
  f16* A2 = (f16*)ws;          ws += (size_t)NB * PP * HH * 2;
  f16* Wt = (f16*)ws;          ws += (size_t)FOURH * K3 * 2;
  f16* xh = (f16*)ws;          ws += (size_t)NB * TT * DD * 2;
  f16* acth0 = (f16*)ws;       ws += (size_t)NB * HH * 2;
  f16* acth1 = (f16*)ws;       ws += (size_t)NB * HH * 2;
  f16* attnb = (f16*)ws;       ws += (size_t)NB * HH * 2;
  float* c0 = (float*)ws;      ws += (size_t)NB * HH * 4;
  float* spart = (float*)ws;   ws += (size_t)NBLK * 256 * 4;
  unsigned* bar = (unsigned*)ws; ws += 4096;

  static int attr_set = 0;
  if (!attr_set) {
    hipFuncSetAttribute((const void*)k_steps,
                        hipFuncAttributeMaxDynamicSharedMemorySize, LDS_BYTES);
    attr_set = 1;
  }

  hipMemsetAsync(bar, 0, 4096, stream);
  k_h0<<<512, 256, 0, stream>>>(A, c0, acth0);
  k_At<<<dim3(7, 32, NB), 256, 0, stream>>>(A, A2);
  k_Wt<<<dim3(96, 128), 256, 0, stream>>>(Wx, Wh, Wa, Wt);
  k_xcvt<<<32768, 256, 0, stream>>>(x, xh);

  void* args[] = { (void*)&xh, (void*)&A2, (void*)&Wt, (void*)&b, (void*)&c0,
                   (void*)&acth0, (void*)&acth1, (void*)&attnb, (void*)&spart,
                   (void*)&out, (void*)&bar };
  hipLaunchCooperativeKernel((const void*)k_steps, dim3(NBLK), dim3(NTHR),
                             args, LDS_BYTES, stream);
}

// Round 4
// 13382.588 us; speedup vs baseline: 2.0720x; 1.8135x over previous
//
#include <hip/hip_runtime.h>
#include <math.h>

typedef _Float16 f16;
typedef f16 f16x4 __attribute__((ext_vector_type(4)));
typedef f16 f16x8 __attribute__((ext_vector_type(8)));
typedef float f32x4 __attribute__((ext_vector_type(4)));

#define NB 128      // batch
#define TT 256      // time steps
#define DD 1024     // input dim
#define HH 1024     // hidden dim
#define PP 196      // spatial positions
#define K3 3072     // folded K = D + H + H
#define FOURH 4096
#define NBLK 256
#define NTHR 512
#define WROW 3078   // LDS row stride (f16): 1539 dw == 3 mod 8 -> <=3-way conflicts
#define LDS_BYTES (16 * WROW * 2 + 9216 * 4)
#define BAR_U32 (4096 + 128 * 64)   // barA | barG | 128 pair flags

// ---------------- P1: h0 = c0 = mean_p A[n][h][:]  ----------------
__global__ void k_h0(const float* __restrict__ A, float* __restrict__ c0,
                     f16* __restrict__ act_h0) {
  int idx = blockIdx.x * 256 + threadIdx.x;
  const float4* ap = (const float4*)(A + (size_t)idx * PP);
  float s = 0.f;
#pragma unroll
  for (int i = 0; i < PP / 4; ++i) { float4 v = ap[i]; s += v.x + v.y + v.z + v.w; }
  float m = s * (1.0f / PP);
  c0[idx] = m;
  act_h0[idx] = (f16)m;
}

// ---------------- P2: A[n][h][p] fp32 -> A2[n][p][h] fp16 ----------------
__global__ void k_At(const float* __restrict__ A, f16* __restrict__ A2) {
  __shared__ float tile[32][33];
  int p0 = blockIdx.x * 32, h0 = blockIdx.y * 32, n = blockIdx.z;
  for (int i = threadIdx.x; i < 1024; i += 256) {
    int r = i >> 5, c = i & 31;
    int p = p0 + c;
    float v = 0.f;
    if (p < PP) v = A[((size_t)n * HH + h0 + r) * PP + p];
    tile[r][c] = v;
  }
  __syncthreads();
  for (int i = threadIdx.x; i < 1024; i += 256) {
    int r = i >> 5, c = i & 31;
    int p = p0 + r;
    if (p < PP) A2[((size_t)n * PP + p) * HH + h0 + c] = (f16)tile[c][r];
  }
}

// ------ P3: Wt[j][k] fp16, col-major weights, k = [Wx;Wh;Wattn] ----------
__global__ void k_Wt(const float* __restrict__ Wx, const float* __restrict__ Wh,
                     const float* __restrict__ Wa, f16* __restrict__ Wt) {
  __shared__ float tile[32][33];
  int k0 = blockIdx.x * 32, j0 = blockIdx.y * 32;
  const float* src; int kb;
  if (k0 < 1024)      { src = Wx; kb = k0; }
  else if (k0 < 2048) { src = Wh; kb = k0 - 1024; }
  else                { src = Wa; kb = k0 - 2048; }
  for (int i = threadIdx.x; i < 1024; i += 256) {
    int r = i >> 5, c = i & 31;
    tile[r][c] = src[(size_t)(kb + r) * FOURH + j0 + c];
  }
  __syncthreads();
  for (int i = threadIdx.x; i < 1024; i += 256) {
    int r = i >> 5, c = i & 31;
    Wt[(size_t)(j0 + r) * K3 + k0 + c] = (f16)tile[c][r];
  }
}

// ---------------- P4: x fp32 -> fp16 ----------------
__global__ void k_xcvt(const float* __restrict__ x, f16* __restrict__ xh) {
  size_t i = (size_t)blockIdx.x * 256 + threadIdx.x;
  float4 v = ((const float4*)x)[i];
  f16x4 o; o[0] = (f16)v.x; o[1] = (f16)v.y; o[2] = (f16)v.z; o[3] = (f16)v.w;
  *(f16x4*)(xh + i * 4) = o;
}

// ------------- relaxed barrier primitives (no wbl2/inv on arrive) ------------
// base: leaves at base[64*i] (i<16), root base[1024], gen base[1040].
__device__ __forceinline__ void bar_arrive(unsigned* base) {
  asm volatile("s_waitcnt vmcnt(0)" ::: "memory");
  unsigned lv = __hip_atomic_fetch_add(base + (blockIdx.x & 15) * 64, 1u,
                                       __ATOMIC_RELAXED, __HIP_MEMORY_SCOPE_AGENT);
  if ((lv & 15u) == 15u) {
    unsigned rv = __hip_atomic_fetch_add(base + 1024, 1u,
                                         __ATOMIC_RELAXED, __HIP_MEMORY_SCOPE_AGENT);
    if ((rv & 15u) == 15u)
      __hip_atomic_fetch_add(base + 1040, 1u,
                             __ATOMIC_RELAXED, __HIP_MEMORY_SCOPE_AGENT);
  }
}
__device__ __forceinline__ void bar_wait_acq(unsigned* base, unsigned target) {
  while (__hip_atomic_load(base + 1040, __ATOMIC_RELAXED,
                           __HIP_MEMORY_SCOPE_AGENT) < target)
    __builtin_amdgcn_s_sleep(2);
  // acquire: single L2 invalidate so subsequent CACHED loads see coherent data
  (void)__hip_atomic_load(base + 1040, __ATOMIC_ACQUIRE, __HIP_MEMORY_SCOPE_AGENT);
}

__device__ __forceinline__ void coh_store_f16(f16* p, f16 v) {
  __hip_atomic_store((short*)p, __builtin_bit_cast(short, v),
                     __ATOMIC_RELAXED, __HIP_MEMORY_SCOPE_AGENT);
}
__device__ __forceinline__ void coh_store_f32(float* p, float v) {
  __hip_atomic_store(p, v, __ATOMIC_RELAXED, __HIP_MEMORY_SCOPE_AGENT);
}
__device__ __forceinline__ float coh_load_f32(const float* p) {
  return __hip_atomic_load(p, __ATOMIC_RELAXED, __HIP_MEMORY_SCOPE_AGENT);
}

// ---------------- persistent per-step kernel (cooperative) ----------------
// 256 blocks x 512 threads, 1 block/CU. A2 slice in registers; Wt slice in LDS.
// Per step: S -> pair-arrive -> G(x,h pre-compute) -> pair-wait -> A ->
//           global barA -> G(attn) + epilogue -> global barG.
__global__ __launch_bounds__(NTHR, 2) void k_steps(
    const f16* __restrict__ xh, const f16* __restrict__ A2,
    const f16* __restrict__ Wtg, const float* __restrict__ bias,
    const float* __restrict__ c0,
    f16* __restrict__ acth0, f16* __restrict__ acth1,
    f16* __restrict__ attnb, float* __restrict__ spart,
    float* __restrict__ out, unsigned* __restrict__ bar) {
  extern __shared__ char smem[];
  f16* wslab = (f16*)smem;                         // [16][WROW]
  float* uni   = (float*)(smem + 16 * WROW * 2);   // 9216 floats
  float* sc    = uni;                              // [208] own score partials
  float* wexp  = uni + 208;                        // [208] softmax weights
  float* srinv = uni + 416;
  float* red   = uni + 512;                        // [16][32][17] attn partials
  float* slabq = uni;                              // G: [4][128][18]

  int tid = threadIdx.x;
  int lane = tid & 63, wid = tid >> 6;
  int bx = blockIdx.x;
  unsigned* barA = bar;
  unsigned* barG = bar + 2048;
  unsigned* pflag = bar + 4096 + (bx >> 1) * 64;

  // ---- S/A geometry ----
  int n = bx >> 1, hhalf = bx & 1;
  int hsub = lane & 31;
  int pg = wid * 2 + (lane >> 5);

  // ---- A2 slice into registers (resident forever) ----
  f16x8 areg0[13], areg1[13];
  {
    const f16* Ab = A2 + ((size_t)n * PP) * HH + hhalf * 512 + hsub * 16;
#pragma unroll
    for (int i = 0; i < 13; ++i) {
      int p = pg + 16 * i; if (p >= PP) p = pg;
      areg0[i] = *(const f16x8*)(Ab + (size_t)p * HH);
      areg1[i] = *(const f16x8*)(Ab + (size_t)p * HH + 8);
    }
  }

  // ---- Wt slice into LDS (resident forever) ----
#pragma unroll 1
  for (int c = 0; c < 16; ++c) {
    if (tid < 384) {
      int j = (c >> 2) * 1024 + bx * 4 + (c & 3);
      f16x8 v = *(const f16x8*)(Wtg + (size_t)j * K3 + tid * 8);
      *(f16x8*)(wslab + c * WROW + tid * 8) = v;
    }
  }

  // ---- G geometry ----
  int l15 = lane & 15, quad = lane >> 4;
  int mhalf = wid & 1, kq = wid >> 1;
  int rowbase = mhalf * 64 + l15;
  const f16* wlp = wslab + l15 * WROW + quad * 8;
  int gn = tid >> 2, gh = tid & 3;
  int hs4 = bx * 4;
  float creg = c0[gn * HH + hs4 + gh];
  float b_i = bias[hs4 + gh], b_f = bias[1024 + hs4 + gh];
  float b_o = bias[2048 + hs4 + gh], b_g = bias[3072 + hs4 + gh];

  for (int t = 0; t < TT; ++t) {
    const f16* hcur = (t & 1) ? acth1 : acth0;
    f16* hnxt = (t & 1) ? acth0 : acth1;
    unsigned tgt = (unsigned)(t + 1);

    // ============ phase S: partial scores over this block's 512 h ============
    {
      const f16x8* hp = (const f16x8*)(hcur + (size_t)n * HH + hhalf * 512 + hsub * 16);
      f16x8 hv0 = hp[0], hv1 = hp[1];
      float hf[16];
#pragma unroll
      for (int e = 0; e < 8; ++e) { hf[e] = (float)hv0[e]; hf[8 + e] = (float)hv1[e]; }
#pragma unroll
      for (int i = 0; i < 13; ++i) {
        float s = 0.f;
#pragma unroll
        for (int e = 0; e < 8; ++e)
          s += hf[e] * (float)areg0[i][e] + hf[8 + e] * (float)areg1[i][e];
        s += __shfl_xor(s, 1, 64);
        s += __shfl_xor(s, 2, 64);
        s += __shfl_xor(s, 4, 64);
        s += __shfl_xor(s, 8, 64);
        s += __shfl_xor(s, 16, 64);
        int p = pg + 16 * i;
        if (hsub == 0 && p < PP) {
          sc[p] = s;
          coh_store_f32(spart + bx * 256 + p, s);
        }
      }
    }
    __syncthreads();                       // drains coherent spart stores
    if (tid == 0)
      __hip_atomic_fetch_add(pflag, 1u, __ATOMIC_RELAXED, __HIP_MEMORY_SCOPE_AGENT);

    // ============ phase Gxh: x-part + h-part of the gates GEMM (no attn dep) =
    f32x4 acc4[4];
#pragma unroll
    for (int i = 0; i < 4; ++i)
#pragma unroll
      for (int e = 0; e < 4; ++e) acc4[i][e] = 0.f;

    auto seg = [&](const f16* base, size_t rstride, int kgbase, int nks) {
#pragma unroll 4
      for (int ks = 0; ks < nks; ++ks) {
        const f16* ap = base + ks * 32 + quad * 8;
        f16x8 b = *(const f16x8*)(wlp + kgbase + ks * 32);
        f16x8 a0 = *(const f16x8*)(ap + (size_t)(rowbase)      * rstride);
        f16x8 a1 = *(const f16x8*)(ap + (size_t)(rowbase + 16) * rstride);
        f16x8 a2 = *(const f16x8*)(ap + (size_t)(rowbase + 32) * rstride);
        f16x8 a3 = *(const f16x8*)(ap + (size_t)(rowbase + 48) * rstride);
        acc4[0] = __builtin_amdgcn_mfma_f32_16x16x32_f16(a0, b, acc4[0], 0, 0, 0);
        acc4[1] = __builtin_amdgcn_mfma_f32_16x16x32_f16(a1, b, acc4[1], 0, 0, 0);
        acc4[2] = __builtin_amdgcn_mfma_f32_16x16x32_f16(a2, b, acc4[2], 0, 0, 0);
        acc4[3] = __builtin_amdgcn_mfma_f32_16x16x32_f16(a3, b, acc4[3], 0, 0, 0);
      }
    };
    {
      const f16* xrow = xh + (size_t)t * DD;
      if (kq == 0)      seg(xrow,        (size_t)TT * DD, 0,    16);
      else if (kq == 1) seg(xrow + 512,  (size_t)TT * DD, 512,  16);
      else if (kq == 2) seg(hcur,        HH,              1024, 16);
      else              seg(hcur + 512,  HH,              1536, 16);
    }

    // ============ pair-wait, then phase A (softmax + attn from registers) ====
    if (tid == 0) {
      while (__hip_atomic_load(pflag, __ATOMIC_RELAXED, __HIP_MEMORY_SCOPE_AGENT)
             < 2u * tgt)
        __builtin_amdgcn_s_sleep(2);
    }
    __syncthreads();
    {
      if (wid == 0) {
        const float* pp = spart + (bx ^ 1) * 256;
        float s0 = (sc[lane]       + coh_load_f32(pp + lane))       * 0.03125f;
        float s1 = (sc[64 + lane]  + coh_load_f32(pp + 64 + lane))  * 0.03125f;
        float s2 = (sc[128 + lane] + coh_load_f32(pp + 128 + lane)) * 0.03125f;
        float s3 = (lane < 4) ? (sc[192 + lane] + coh_load_f32(pp + 192 + lane)) * 0.03125f
                              : -1e30f;
        float mx = fmaxf(fmaxf(s0, s1), fmaxf(s2, s3));
#pragma unroll
        for (int off = 32; off > 0; off >>= 1) mx = fmaxf(mx, __shfl_xor(mx, off, 64));
        float e0 = __expf(s0 - mx), e1 = __expf(s1 - mx), e2 = __expf(s2 - mx);
        float e3 = (lane < 4) ? __expf(s3 - mx) : 0.f;
        float ssum = e0 + e1 + e2 + e3;
#pragma unroll
        for (int off = 32; off > 0; off >>= 1) ssum += __shfl_xor(ssum, off, 64);
        wexp[lane] = e0; wexp[64 + lane] = e1; wexp[128 + lane] = e2;
        if (lane < 4)  wexp[192 + lane] = e3;
        if (lane < 12) wexp[196 + lane] = 0.f;
        if (lane == 0) *srinv = 1.f / ssum;
      }
      __syncthreads();
      float acc[16];
#pragma unroll
      for (int e = 0; e < 16; ++e) acc[e] = 0.f;
#pragma unroll
      for (int i = 0; i < 13; ++i) {
        float wgt = wexp[pg + 16 * i];
#pragma unroll
        for (int e = 0; e < 8; ++e) {
          acc[e]     += wgt * (float)areg0[i][e];
          acc[8 + e] += wgt * (float)areg1[i][e];
        }
      }
#pragma unroll
      for (int e = 0; e < 16; ++e) red[pg * 544 + hsub * 17 + e] = acc[e];
      __syncthreads();
      float s = 0.f;
      int ra = (tid >> 4) * 17 + (tid & 15);
#pragma unroll
      for (int g = 0; g < 16; ++g) s += red[g * 544 + ra];
      coh_store_f16(attnb + (size_t)n * HH + hhalf * 512 + tid,
                    (f16)(s * (*srinv)));
    }
    __syncthreads();                       // drains coherent attnb stores
    if (tid == 0) { bar_arrive(barA); bar_wait_acq(barA, tgt); }
    __syncthreads();

    // ============ phase Gattn: attn-part of GEMM + LSTM epilogue =============
    seg(attnb + kq * 256, HH, 2048 + kq * 256, 8);

#pragma unroll
    for (int mt = 0; mt < 4; ++mt)
#pragma unroll
      for (int jr = 0; jr < 4; ++jr)
        slabq[kq * 2304 + (mhalf * 64 + mt * 16 + quad * 4 + jr) * 18 + l15] =
            acc4[mt][jr];
    __syncthreads();
    {
      float ai = b_i, af = b_f, ao = b_o, ag = b_g;
#pragma unroll
      for (int q = 0; q < 4; ++q) {
        const float* sl = slabq + q * 2304 + gn * 18;
        ai += sl[gh]; af += sl[4 + gh]; ao += sl[8 + gh]; ag += sl[12 + gh];
      }
      float ig = 1.f / (1.f + __expf(-ai));
      float fg = 1.f / (1.f + __expf(-af));
      float og = 1.f / (1.f + __expf(-ao));
      float gg = tanhf(ag);
      creg = fg * creg + ig * gg;
      float hn = og * tanhf(creg);
      __builtin_nontemporal_store(hn, &out[((size_t)gn * TT + t) * HH + hs4 + gh]);
      coh_store_f16(hnxt + gn * HH + hs4 + gh, (f16)hn);
    }
    __syncthreads();                       // drains coherent acth stores
    if (tid == 0) { bar_arrive(barG); bar_wait_acq(barG, tgt); }
    __syncthreads();
  }
}

extern "C" void kernel_launch(void* const* d_in, const int* in_sizes, int n_in,
                              void* d_out, int out_size, void* d_ws, size_t ws_size,
                              hipStream_t stream) {
  const float* x  = (const float*)d_in[0];
  const float* A  = (const float*)d_in[1];
  const float* Wx = (const float*)d_in[2];
  const float* Wh = (const float*)d_in[3];
  const float* Wa = (const float*)d_in[4];
  const float* b  = (const float*)d_in[5];
  float* out = (float*)d_out;

  char* ws = (char*)d_ws;
  f16* A2 = (f16*)ws;          ws += (size_t)NB * PP * HH * 2;
  f16* Wt = (f16*)ws;          ws += (size_t)FOURH * K3 * 2;
  f16* xh = (f16*)ws;          ws += (size_t)NB * TT * DD * 2;
  f16* acth0 = (f16*)ws;       ws += (size_t)NB * HH * 2;
  f16* acth1 = (f16*)ws;       ws += (size_t)NB * HH * 2;
  f16* attnb = (f16*)ws;       ws += (size_t)NB * HH * 2;
  float* c0 = (float*)ws;      ws += (size_t)NB * HH * 4;
  float* spart = (float*)ws;   ws += (size_t)NBLK * 256 * 4;
  unsigned* bar = (unsigned*)ws; ws += (size_t)BAR_U32 * 4;

  static int attr_set = 0;
  if (!attr_set) {
    hipFuncSetAttribute((const void*)k_steps,
                        hipFuncAttributeMaxDynamicSharedMemorySize, LDS_BYTES);
    attr_set = 1;
  }

  hipMemsetAsync(bar, 0, BAR_U32 * 4, stream);
  k_h0<<<512, 256, 0, stream>>>(A, c0, acth0);
  k_At<<<dim3(7, 32, NB), 256, 0, stream>>>(A, A2);
  k_Wt<<<dim3(96, 128), 256, 0, stream>>>(Wx, Wh, Wa, Wt);
  k_xcvt<<<32768, 256, 0, stream>>>(x, xh);

  void* args[] = { (void*)&xh, (void*)&A2, (void*)&Wt, (void*)&b, (void*)&c0,
                   (void*)&acth0, (void*)&acth1, (void*)&attnb, (void*)&spart,
                   (void*)&out, (void*)&bar };
  hipLaunchCooperativeKernel((const void*)k_steps, dim3(NBLK), dim3(NTHR),
                             args, LDS_BYTES, stream);
}